// Round 15
// baseline (96.340 us; speedup 1.0000x reference)
//
#include <hip/hip_runtime.h>
#include <stdint.h>

// pooled[b,o] = x[b,:] . Wp[o,:] + biasp[o] + 0.25*(y[b,n0]+y[b,n0+1]+y[b,n0+64]+y[b,n0+65])
//   o = p*32+q, n0 = 128p+2q; Wp = 2x2-pooled W rows. out = pooled / mean(pooled).
// Analytic mean (bilinearity): S = sx.swp + B*sum(biasp) + 0.25*sum(y), where
// sx = column-sums of x, swp = 0.25*column-sums of W. inv known BEFORE gemm ->
// gemm epilogue scales and writes final f32 out directly; norm pass deleted.
// 3 dispatches: prep (x->bf16, pool W/bias, y/x/W reductions) -> combine
// (1 block -> inv) -> gemm (r11 schedule: 256x128, 1 barrier + vmcnt/tile).

#define KDIM 1024
#define NP   1024
#define BM 256
#define BN 128
#define BK 64
#define NBLK 256

typedef __bf16 bf16x8 __attribute__((ext_vector_type(8)));
typedef float f32x4 __attribute__((ext_vector_type(4)));

__device__ __forceinline__ unsigned f2bf(float f) {
  union { float f; unsigned u; } v; v.f = f;
  unsigned r = v.u + 0x7fffu + ((v.u >> 16) & 1u);  // RNE
  return r >> 16;
}

__device__ __forceinline__ void gload_lds16(const void* g, void* l) {
  __builtin_amdgcn_global_load_lds(
      (const __attribute__((address_space(1))) void*)g,
      (__attribute__((address_space(3))) void*)l, 16, 0, 0);
}

// ---- kernel 1: x->bf16 (0..4095) | W-pool (4096..5119) | y-sum (5120..5631)
//                | x-colsum (5632..5663) | W-colsum (5664..5679) ----
__global__ void k_prep(const float* __restrict__ x, const float* __restrict__ W,
                       const float* __restrict__ bias, const float* __restrict__ y,
                       unsigned short* __restrict__ xb, unsigned short* __restrict__ wp,
                       float* __restrict__ biasp, float* __restrict__ sxpart,
                       float* __restrict__ swpart, float* __restrict__ ypart) {
  int b = blockIdx.x;
  int t = threadIdx.x;
  if (b < 4096) {
    int i = b * 256 + t;  // 8 elems per thread
    const float4* x4 = (const float4*)x;
    float4 a = x4[i * 2], c = x4[i * 2 + 1];
    uint4 o;
    o.x = f2bf(a.x) | (f2bf(a.y) << 16);
    o.y = f2bf(a.z) | (f2bf(a.w) << 16);
    o.z = f2bf(c.x) | (f2bf(c.y) << 16);
    o.w = f2bf(c.z) | (f2bf(c.w) << 16);
    ((uint4*)xb)[i] = o;
  } else if (b < 5120) {
    int o = b - 4096;  // pooled feature index
    int r0 = ((o >> 5) << 7) + ((o & 31) << 1);
    const float4* W4 = (const float4*)W;
    float4 w0 = W4[(r0) * 256 + t];
    float4 w1 = W4[(r0 + 1) * 256 + t];
    float4 w2 = W4[(r0 + 64) * 256 + t];
    float4 w3 = W4[(r0 + 65) * 256 + t];
    float ax = 0.25f * (w0.x + w1.x + w2.x + w3.x);
    float ay = 0.25f * (w0.y + w1.y + w2.y + w3.y);
    float az = 0.25f * (w0.z + w1.z + w2.z + w3.z);
    float aw = 0.25f * (w0.w + w1.w + w2.w + w3.w);
    uint2 pk;
    pk.x = f2bf(ax) | (f2bf(ay) << 16);
    pk.y = f2bf(az) | (f2bf(aw) << 16);
    ((uint2*)wp)[o * 256 + t] = pk;
    if (t == 0)
      biasp[o] = 0.25f * (bias[r0] + bias[r0 + 1] + bias[r0 + 64] + bias[r0 + 65]);
  } else if (b < 5632) {
    // y-sum: 512 blocks x 16384 float4 each (y = 8.4M float4 total)
    int j = b - 5120;
    const float4* y4 = (const float4*)y + (size_t)j * 16384;
    float s0 = 0.f, s1 = 0.f;
#pragma unroll 8
    for (int i = 0; i < 64; i += 2) {
      float4 u = y4[i * 256 + t];
      float4 v = y4[(i + 1) * 256 + t];
      s0 += (u.x + u.y) + (u.z + u.w);
      s1 += (v.x + v.y) + (v.z + v.w);
    }
    float s = s0 + s1;
#pragma unroll
    for (int off = 32; off > 0; off >>= 1) s += __shfl_down(s, off);
    __shared__ float sm[4];
    if ((t & 63) == 0) sm[t >> 6] = s;
    __syncthreads();
    if (t == 0) ypart[j] = (sm[0] + sm[1]) + (sm[2] + sm[3]);
  } else if (b < 5664) {
    // x column sums: 32 blocks x 256 rows; thread t owns cols t,+256,+512,+768
    int j = b - 5632;
    const float* base = x + (size_t)j * 256 * 1024;
    float s0 = 0.f, s1 = 0.f, s2 = 0.f, s3 = 0.f;
    for (int r = 0; r < 256; ++r) {
      const float* row = base + (size_t)r * 1024;
      s0 += row[t];
      s1 += row[t + 256];
      s2 += row[t + 512];
      s3 += row[t + 768];
    }
    sxpart[j * 1024 + t] = s0;
    sxpart[j * 1024 + t + 256] = s1;
    sxpart[j * 1024 + t + 512] = s2;
    sxpart[j * 1024 + t + 768] = s3;
  } else {
    // W column sums: 16 blocks x 256 rows (covers all 4096 W rows once)
    int j = b - 5664;
    const float* base = W + (size_t)j * 256 * 1024;
    float s0 = 0.f, s1 = 0.f, s2 = 0.f, s3 = 0.f;
    for (int r = 0; r < 256; ++r) {
      const float* row = base + (size_t)r * 1024;
      s0 += row[t];
      s1 += row[t + 256];
      s2 += row[t + 512];
      s3 += row[t + 768];
    }
    swpart[j * 1024 + t] = s0;
    swpart[j * 1024 + t + 256] = s1;
    swpart[j * 1024 + t + 512] = s2;
    swpart[j * 1024 + t + 768] = s3;
  }
}

// ---- kernel 2: combine partials -> inv (1 block, deterministic order) ----
__global__ void k_combine(const float* __restrict__ sxpart, const float* __restrict__ swpart,
                          const float* __restrict__ ypart, const float* __restrict__ biasp,
                          float* __restrict__ inv) {
  __shared__ float sd[256], sb[256], sy[256];
  int t = threadIdx.x;
  float d = 0.f, bsum = 0.f;
#pragma unroll
  for (int c = 0; c < 4; ++c) {
    int k = t + 256 * c;
    float sxk = 0.f;
#pragma unroll
    for (int j = 0; j < 32; ++j) sxk += sxpart[j * 1024 + k];
    float swk = 0.f;
#pragma unroll
    for (int j = 0; j < 16; ++j) swk += swpart[j * 1024 + k];
    d += sxk * (0.25f * swk);  // swp = 0.25 * colsum(W)
    bsum += biasp[k];
  }
  sd[t] = d;
  sb[t] = bsum;
  sy[t] = ypart[t] + ypart[t + 256];
  __syncthreads();
#pragma unroll
  for (int off = 128; off > 0; off >>= 1) {
    if (t < off) { sd[t] += sd[t + off]; sb[t] += sb[t + off]; sy[t] += sy[t + off]; }
    __syncthreads();
  }
  if (t == 0) {
    float S = sd[0] + 8192.0f * sb[0] + 0.25f * sy[0];
    inv[0] = 8388608.0f / S;  // (B*NP)/total
  }
}

// ---- kernel 3: GEMM 256x128, 1 barrier + 1 vmcnt per K-tile (r11 schedule);
//      epilogue scales by precomputed inv and writes final f32 out ----
__global__ __launch_bounds__(512, 2) void k_gemm(
    const unsigned short* __restrict__ xb, const unsigned short* __restrict__ wp,
    const float* __restrict__ biasp, const float* __restrict__ y,
    float* __restrict__ out, const float* __restrict__ inv) {
  // buf in {0,1}: A(buf)=smem+buf*49152 (32KB), B(buf)=+32768 (16KB)
  __shared__ char smem[98304];

  int bid = blockIdx.x;
  int wg = (bid & 7) * 32 + (bid >> 3);  // XCD swizzle, 256 = 8*32 bijective
  int bm0 = (wg >> 3) * BM;   // 32 row tiles
  int bn0 = (wg & 7) * BN;    // 8 col tiles

  int tid = threadIdx.x;
  int lane = tid & 63;
  int wid = tid >> 6;               // 0..7
  int wr = wid >> 1, wc = wid & 1;  // wave tile 64x64

  f32x4 acc[4][4];
#pragma unroll
  for (int i = 0; i < 4; i++)
#pragma unroll
    for (int j = 0; j < 4; j++) acc[i][j] = (f32x4)0.0f;

  // staging: 512 thr x 16B = 8KB/call; A 32KB = 4 calls, B 16KB = 2 calls.
  // LDS dest linear; SOURCE col chunk pre-swizzled by (lane&7)^(lane>>3).
  int srow = tid >> 3;  // 0..63
  int scol = (((lane & 7) ^ (lane >> 3)) << 3);
  const unsigned short* aSrc = xb + (size_t)(bm0 + srow) * KDIM + scol;
  const unsigned short* bSrc = wp + (size_t)(bn0 + srow) * KDIM + scol;
  int ldsOff = wid * 1024;

  int rbase = (lane & 15) * 128;
  int xorv = (lane & 7) << 4;
  int cb0 = (((lane >> 4) * 16)) ^ xorv;
  int cb1 = ((64 + (lane >> 4) * 16)) ^ xorv;

  // y: tile p covers fragment (mi=p>>2, ni=p&3), j=0..3 -> 8 dwordx2/tile.
  const float2* y2 = (const float2*)y;
  int r_l = (lane >> 4) * 4;
  int c_l = lane & 15;
  int yrb = bm0 + wr * 64 + r_l;
  int yb[4];
#pragma unroll
  for (int ni = 0; ni < 4; ++ni) {
    int col = bn0 + wc * 64 + ni * 16 + c_l;
    yb[ni] = ((col >> 5) << 6) + (col & 31);
  }
  float2 yin[2][8];  // 2-slot rotating window

#define STAGE_P1(buf, ks)                                                      \
  {                                                                            \
    int k0 = (ks) * BK;                                                        \
    char* ab = smem + (buf) * 49152 + ldsOff;                                  \
    gload_lds16(aSrc + k0, ab);                                                \
    gload_lds16(aSrc + (size_t)64 * KDIM + k0, ab + 8192);                     \
    gload_lds16(aSrc + (size_t)128 * KDIM + k0, ab + 16384);                   \
  }
#define STAGE_P2(buf, ks)                                                      \
  {                                                                            \
    int k0 = (ks) * BK;                                                        \
    char* ab = smem + (buf) * 49152 + ldsOff;                                  \
    char* bb = smem + (buf) * 49152 + 32768 + ldsOff;                          \
    gload_lds16(aSrc + (size_t)192 * KDIM + k0, ab + 24576);                   \
    gload_lds16(bSrc + k0, bb);                                                \
    gload_lds16(bSrc + (size_t)64 * KDIM + k0, bb + 8192);                     \
  }

#define YLD2(slot, s, q)                                                       \
  {                                                                            \
    const float2* pp = y2 +                                                    \
        (size_t)(yrb + (((q) >> 4) * 16) + ((q) & 3)) * 2048 + yb[((q) >> 2) & 3]; \
    asm volatile("global_load_dwordx2 %0, %1, off"                             \
                 : "=v"(yin[slot][2 * (s)]) : "v"(pp) : "memory");             \
    asm volatile("global_load_dwordx2 %0, %1, off offset:256"                  \
                 : "=v"(yin[slot][2 * (s) + 1]) : "v"(pp) : "memory");         \
  }
#define YLOAD8(slot, t)                                                        \
  { YLD2(slot, 0, 4 * (t)) YLD2(slot, 1, 4 * (t) + 1)                          \
    YLD2(slot, 2, 4 * (t) + 2) YLD2(slot, 3, 4 * (t) + 3) }
#define YCONS4(slot, p)                                                        \
  {                                                                            \
    _Pragma("unroll")                                                          \
    for (int s = 0; s < 4; ++s)                                                \
      acc[(p) >> 2][(p) & 3][s] +=                                             \
          0.25f * ((yin[slot][2 * s].x + yin[slot][2 * s].y) +                 \
                   (yin[slot][2 * s + 1].x + yin[slot][2 * s + 1].y));         \
  }

#define FRAGS(av, bv, cbv, Ab, Bb)                                             \
  {                                                                            \
    _Pragma("unroll")                                                          \
    for (int mi = 0; mi < 4; ++mi)                                             \
      av[mi] = *(const bf16x8*)((Ab) + (wr * 64 + mi * 16) * 128 + rbase + (cbv)); \
    _Pragma("unroll")                                                          \
    for (int ni = 0; ni < 4; ++ni)                                             \
      bv[ni] = *(const bf16x8*)((Bb) + (wc * 64 + ni * 16) * 128 + rbase + (cbv)); \
  }
#define MM16(av, bv)                                                           \
  {                                                                            \
    _Pragma("unroll")                                                          \
    for (int mi = 0; mi < 4; ++mi)                                             \
      _Pragma("unroll")                                                        \
      for (int ni = 0; ni < 4; ++ni)                                           \
        acc[mi][ni] = __builtin_amdgcn_mfma_f32_16x16x32_bf16(                 \
            av[mi], bv[ni], acc[mi][ni], 0, 0, 0);                             \
  }

#define TILE(t, WSTR)                                                          \
  {                                                                            \
    asm volatile(WSTR ::: "memory");                                           \
    __builtin_amdgcn_sched_barrier(0);                                         \
    __builtin_amdgcn_s_barrier();                                              \
    if ((t) >= 2) YCONS4(((t) - 2) & 1, (t) - 2);                              \
    const char* Ab = smem + ((t) & 1) * 49152;                                 \
    const char* Bb = Ab + 32768;                                               \
    bf16x8 a0[4], b0[4];                                                       \
    FRAGS(a0, b0, cb0, Ab, Bb);                                                \
    if ((t) < 15) STAGE_P1(((t) + 1) & 1, (t) + 1);                            \
    asm volatile("s_waitcnt lgkmcnt(0)" ::: "memory");                         \
    __builtin_amdgcn_sched_barrier(0);                                         \
    __builtin_amdgcn_s_setprio(1);                                             \
    MM16(a0, b0);                                                              \
    __builtin_amdgcn_s_setprio(0);                                             \
    bf16x8 a1[4], b1[4];                                                       \
    FRAGS(a1, b1, cb1, Ab, Bb);                                                \
    if ((t) < 15) STAGE_P2(((t) + 1) & 1, (t) + 1);                            \
    YLOAD8((t) & 1, t);                                                        \
    asm volatile("s_waitcnt lgkmcnt(0)" ::: "memory");                         \
    __builtin_amdgcn_sched_barrier(0);                                         \
    __builtin_amdgcn_s_setprio(1);                                             \
    MM16(a1, b1);                                                              \
    __builtin_amdgcn_s_setprio(0);                                             \
  }

  STAGE_P1(0, 0);
  STAGE_P2(0, 0);

  TILE(0,  "s_waitcnt vmcnt(0)")
  TILE(1,  "s_waitcnt vmcnt(8)")
  TILE(2,  "s_waitcnt vmcnt(8)")
  TILE(3,  "s_waitcnt vmcnt(8)")
  TILE(4,  "s_waitcnt vmcnt(8)")
  TILE(5,  "s_waitcnt vmcnt(8)")
  TILE(6,  "s_waitcnt vmcnt(8)")
  TILE(7,  "s_waitcnt vmcnt(8)")
  TILE(8,  "s_waitcnt vmcnt(8)")
  TILE(9,  "s_waitcnt vmcnt(8)")
  TILE(10, "s_waitcnt vmcnt(8)")
  TILE(11, "s_waitcnt vmcnt(8)")
  TILE(12, "s_waitcnt vmcnt(8)")
  TILE(13, "s_waitcnt vmcnt(8)")
  TILE(14, "s_waitcnt vmcnt(8)")
  TILE(15, "s_waitcnt vmcnt(8)")

  asm volatile("s_waitcnt vmcnt(0)" ::: "memory");
  __builtin_amdgcn_sched_barrier(0);
  YCONS4(0, 14);
  YCONS4(1, 15);

  // epilogue: acc holds gemm + pooled y; add bias, scale by inv, store f32
  float iv = inv[0];
  float bpv[4];
#pragma unroll
  for (int ni = 0; ni < 4; ++ni) bpv[ni] = biasp[bn0 + wc * 64 + ni * 16 + c_l];
#pragma unroll
  for (int mi = 0; mi < 4; ++mi) {
#pragma unroll
    for (int ni = 0; ni < 4; ++ni) {
      int col = bn0 + wc * 64 + ni * 16 + c_l;
#pragma unroll
      for (int j = 0; j < 4; ++j) {
        int row = bm0 + wr * 64 + mi * 16 + r_l + j;
        out[(size_t)row * NP + col] = (acc[mi][ni][j] + bpv[ni]) * iv;
      }
    }
  }
}

extern "C" void kernel_launch(void* const* d_in, const int* in_sizes, int n_in,
                              void* d_out, int out_size, void* d_ws, size_t ws_size,
                              hipStream_t stream) {
  (void)in_sizes; (void)n_in; (void)out_size; (void)ws_size;
  const float* x = (const float*)d_in[0];
  const float* y = (const float*)d_in[1];
  const float* W = (const float*)d_in[2];
  const float* bias = (const float*)d_in[3];
  float* out = (float*)d_out;

  char* ws = (char*)d_ws;
  unsigned short* xb = (unsigned short*)(ws);            // 16 MiB
  unsigned short* wp = (unsigned short*)(ws + 16777216); // 2 MiB
  float* biasp = (float*)(ws + 18874368);                // 4 KiB
  float* sxpart = (float*)(ws + 18878464);               // 128 KiB (32x1024)
  float* swpart = (float*)(ws + 19009536);               // 64 KiB (16x1024)
  float* ypart = (float*)(ws + 19075072);                // 2 KiB (512)
  float* invp = (float*)(ws + 19077120);                 // 4 B

  hipLaunchKernelGGL(k_prep, dim3(5680), dim3(256), 0, stream,
                     x, W, bias, y, xb, wp, biasp, sxpart, swpart, ypart);
  hipLaunchKernelGGL(k_combine, dim3(1), dim3(256), 0, stream,
                     sxpart, swpart, ypart, biasp, invp);
  hipLaunchKernelGGL(k_gemm, dim3(NBLK), dim3(512), 0, stream,
                     xb, wp, biasp, y, out, invp);
}

// Round 17
// 80.147 us; speedup vs baseline: 1.2020x; 1.2020x over previous
//
#include <hip/hip_runtime.h>
#include <stdint.h>

// pooled[b,o] = x[b,:] . Wp[o,:] + biasp[o] + 0.25*(y[b,n0]+y[b,n0+1]+y[b,n0+64]+y[b,n0+65])
//   o = p*32+q, n0 = 128p+2q; Wp = 2x2-pooled W rows. out = pooled / mean(pooled).
// Analytic mean: S = sum_k sx[k]*swp[k] + B*sum(biasp) + 0.25*sum(y), with
// sx = colsum(x) (fused into the x->bf16 convert, no extra reads) and
// swp = colsum(wp) (wp is ALREADY 0.25-pooled -> no extra factor!).
// inv known before gemm -> gemm scales in epilogue, writes final f32 out.
// 3 dispatches: prep -> reduce2 (16 blocks -> dotpart) -> gemm (r11 schedule,
// redundant per-block inv reduce in prologue).

#define KDIM 1024
#define NP   1024
#define BM 256
#define BN 128
#define BK 64
#define NBLK 256

typedef __bf16 bf16x8 __attribute__((ext_vector_type(8)));
typedef float f32x4 __attribute__((ext_vector_type(4)));

__device__ __forceinline__ unsigned f2bf(float f) {
  union { float f; unsigned u; } v; v.f = f;
  unsigned r = v.u + 0x7fffu + ((v.u >> 16) & 1u);  // RNE
  return r >> 16;
}
__device__ __forceinline__ float bf2f(unsigned short h) {
  union { unsigned u; float f; } v; v.u = ((unsigned)h) << 16;
  return v.f;
}

__device__ __forceinline__ void gload_lds16(const void* g, void* l) {
  __builtin_amdgcn_global_load_lds(
      (const __attribute__((address_space(1))) void*)g,
      (__attribute__((address_space(3))) void*)l, 16, 0, 0);
}

// ---- kernel 1: blocks 0..511 x->bf16 + colsum | 512..1535 W-pool | 1536..2047 y-sum ----
__global__ void k_prep(const float* __restrict__ x, const float* __restrict__ W,
                       const float* __restrict__ bias, const float* __restrict__ y,
                       unsigned short* __restrict__ xb, unsigned short* __restrict__ wp,
                       float* __restrict__ biasp, float* __restrict__ sxpart,
                       float* __restrict__ ypart) {
  int b = blockIdx.x;
  int t = threadIdx.x;
  if (b < 512) {
    // convert 16 rows + accumulate column sums (thread t owns cols 4t..4t+3)
    const float4* x4 = (const float4*)x;
    uint2* xb2 = (uint2*)xb;
    float4 cs = {0.f, 0.f, 0.f, 0.f};
#pragma unroll
    for (int r = 0; r < 16; ++r) {
      int row = b * 16 + r;
      float4 f = x4[(size_t)row * 256 + t];
      uint2 pk;
      pk.x = f2bf(f.x) | (f2bf(f.y) << 16);
      pk.y = f2bf(f.z) | (f2bf(f.w) << 16);
      xb2[(size_t)row * 256 + t] = pk;
      cs.x += f.x; cs.y += f.y; cs.z += f.z; cs.w += f.w;
    }
    ((float4*)sxpart)[b * 256 + t] = cs;
  } else if (b < 1536) {
    int o = b - 512;  // pooled feature index
    int r0 = ((o >> 5) << 7) + ((o & 31) << 1);
    const float4* W4 = (const float4*)W;
    float4 w0 = W4[(r0) * 256 + t];
    float4 w1 = W4[(r0 + 1) * 256 + t];
    float4 w2 = W4[(r0 + 64) * 256 + t];
    float4 w3 = W4[(r0 + 65) * 256 + t];
    float ax = 0.25f * (w0.x + w1.x + w2.x + w3.x);
    float ay = 0.25f * (w0.y + w1.y + w2.y + w3.y);
    float az = 0.25f * (w0.z + w1.z + w2.z + w3.z);
    float aw = 0.25f * (w0.w + w1.w + w2.w + w3.w);
    uint2 pk;
    pk.x = f2bf(ax) | (f2bf(ay) << 16);
    pk.y = f2bf(az) | (f2bf(aw) << 16);
    ((uint2*)wp)[o * 256 + t] = pk;
    if (t == 0)
      biasp[o] = 0.25f * (bias[r0] + bias[r0 + 1] + bias[r0 + 64] + bias[r0 + 65]);
  } else {
    // y-sum: 512 blocks x 16384 float4 each
    int j = b - 1536;
    const float4* y4 = (const float4*)y + (size_t)j * 16384;
    float s0 = 0.f, s1 = 0.f;
#pragma unroll 8
    for (int i = 0; i < 64; i += 2) {
      float4 u = y4[i * 256 + t];
      float4 v = y4[(i + 1) * 256 + t];
      s0 += (u.x + u.y) + (u.z + u.w);
      s1 += (v.x + v.y) + (v.z + v.w);
    }
    float s = s0 + s1;
#pragma unroll
    for (int off = 32; off > 0; off >>= 1) s += __shfl_down(s, off);
    __shared__ float sm[4];
    if ((t & 63) == 0) sm[t >> 6] = s;
    __syncthreads();
    if (t == 0) ypart[j] = (sm[0] + sm[1]) + (sm[2] + sm[3]);
  }
}

// ---- kernel 2: per-column reduce of sxpart + colsum(wp) -> partial dots ----
__global__ void k_reduce2(const float* __restrict__ sxpart,
                          const unsigned short* __restrict__ wp,
                          float* __restrict__ dotpart) {
  __shared__ float sxs[4][64], sws[4][64];
  int r = blockIdx.x;        // 0..15, covers cols r*64..r*64+63
  int t = threadIdx.x;
  int col = r * 64 + (t & 63);
  int chunk = t >> 6;        // 0..3
  float sx = 0.f;
  for (int j = chunk * 128; j < chunk * 128 + 128; ++j)
    sx += sxpart[j * 1024 + col];
  float sw = 0.f;
  for (int row = chunk * 256; row < chunk * 256 + 256; ++row)
    sw += bf2f(wp[(size_t)row * 1024 + col]);
  sxs[chunk][t & 63] = sx;
  sws[chunk][t & 63] = sw;
  __syncthreads();
  if (t < 64) {
    float scol = (sxs[0][t] + sxs[1][t]) + (sxs[2][t] + sxs[3][t]);
    float wcol = (sws[0][t] + sws[1][t]) + (sws[2][t] + sws[3][t]);
    float v = scol * wcol;  // wp already carries the 0.25 pooling factor
#pragma unroll
    for (int off = 32; off > 0; off >>= 1) v += __shfl_down(v, off);
    if (t == 0) dotpart[r] = v;
  }
}

// ---- kernel 3: GEMM 256x128 (r11 schedule); redundant inv reduce in prologue;
//      epilogue scales by inv, writes final f32 out ----
__global__ __launch_bounds__(512, 2) void k_gemm(
    const unsigned short* __restrict__ xb, const unsigned short* __restrict__ wp,
    const float* __restrict__ biasp, const float* __restrict__ y,
    float* __restrict__ out, const float* __restrict__ dotpart,
    const float* __restrict__ ypart) {
  // buf in {0,1}: A(buf)=smem+buf*49152 (32KB), B(buf)=+32768 (16KB)
  __shared__ char smem[98304];

  int bid = blockIdx.x;
  int wg = (bid & 7) * 32 + (bid >> 3);  // XCD swizzle, 256 = 8*32 bijective
  int bm0 = (wg >> 3) * BM;   // 32 row tiles
  int bn0 = (wg & 7) * BN;    // 8 col tiles

  int tid = threadIdx.x;
  int lane = tid & 63;
  int wid = tid >> 6;               // 0..7
  int wr = wid >> 1, wc = wid & 1;  // wave tile 64x64

  f32x4 acc[4][4];
#pragma unroll
  for (int i = 0; i < 4; i++)
#pragma unroll
    for (int j = 0; j < 4; j++) acc[i][j] = (f32x4)0.0f;

  int srow = tid >> 3;  // 0..63
  int scol = (((lane & 7) ^ (lane >> 3)) << 3);
  const unsigned short* aSrc = xb + (size_t)(bm0 + srow) * KDIM + scol;
  const unsigned short* bSrc = wp + (size_t)(bn0 + srow) * KDIM + scol;
  int ldsOff = wid * 1024;

  int rbase = (lane & 15) * 128;
  int xorv = (lane & 7) << 4;
  int cb0 = (((lane >> 4) * 16)) ^ xorv;
  int cb1 = ((64 + (lane >> 4) * 16)) ^ xorv;

  // y: tile p covers fragment (mi=p>>2, ni=p&3), j=0..3 -> 8 dwordx2/tile.
  const float2* y2 = (const float2*)y;
  int r_l = (lane >> 4) * 4;
  int c_l = lane & 15;
  int yrb = bm0 + wr * 64 + r_l;
  int yb[4];
#pragma unroll
  for (int ni = 0; ni < 4; ++ni) {
    int col = bn0 + wc * 64 + ni * 16 + c_l;
    yb[ni] = ((col >> 5) << 6) + (col & 31);
  }
  float2 yin[2][8];  // 2-slot rotating window

#define STAGE_P1(buf, ks)                                                      \
  {                                                                            \
    int k0 = (ks) * BK;                                                        \
    char* ab = smem + (buf) * 49152 + ldsOff;                                  \
    gload_lds16(aSrc + k0, ab);                                                \
    gload_lds16(aSrc + (size_t)64 * KDIM + k0, ab + 8192);                     \
    gload_lds16(aSrc + (size_t)128 * KDIM + k0, ab + 16384);                   \
  }
#define STAGE_P2(buf, ks)                                                      \
  {                                                                            \
    int k0 = (ks) * BK;                                                        \
    char* ab = smem + (buf) * 49152 + ldsOff;                                  \
    char* bb = smem + (buf) * 49152 + 32768 + ldsOff;                          \
    gload_lds16(aSrc + (size_t)192 * KDIM + k0, ab + 24576);                   \
    gload_lds16(bSrc + k0, bb);                                                \
    gload_lds16(bSrc + (size_t)64 * KDIM + k0, bb + 8192);                     \
  }

#define YLD2(slot, s, q)                                                       \
  {                                                                            \
    const float2* pp = y2 +                                                    \
        (size_t)(yrb + (((q) >> 4) * 16) + ((q) & 3)) * 2048 + yb[((q) >> 2) & 3]; \
    asm volatile("global_load_dwordx2 %0, %1, off"                             \
                 : "=v"(yin[slot][2 * (s)]) : "v"(pp) : "memory");             \
    asm volatile("global_load_dwordx2 %0, %1, off offset:256"                  \
                 : "=v"(yin[slot][2 * (s) + 1]) : "v"(pp) : "memory");         \
  }
#define YLOAD8(slot, t)                                                        \
  { YLD2(slot, 0, 4 * (t)) YLD2(slot, 1, 4 * (t) + 1)                          \
    YLD2(slot, 2, 4 * (t) + 2) YLD2(slot, 3, 4 * (t) + 3) }
#define YCONS4(slot, p)                                                        \
  {                                                                            \
    _Pragma("unroll")                                                          \
    for (int s = 0; s < 4; ++s)                                                \
      acc[(p) >> 2][(p) & 3][s] +=                                             \
          0.25f * ((yin[slot][2 * s].x + yin[slot][2 * s].y) +                 \
                   (yin[slot][2 * s + 1].x + yin[slot][2 * s + 1].y));         \
  }

#define FRAGS(av, bv, cbv, Ab, Bb)                                             \
  {                                                                            \
    _Pragma("unroll")                                                          \
    for (int mi = 0; mi < 4; ++mi)                                             \
      av[mi] = *(const bf16x8*)((Ab) + (wr * 64 + mi * 16) * 128 + rbase + (cbv)); \
    _Pragma("unroll")                                                          \
    for (int ni = 0; ni < 4; ++ni)                                             \
      bv[ni] = *(const bf16x8*)((Bb) + (wc * 64 + ni * 16) * 128 + rbase + (cbv)); \
  }
#define MM16(av, bv)                                                           \
  {                                                                            \
    _Pragma("unroll")                                                          \
    for (int mi = 0; mi < 4; ++mi)                                             \
      _Pragma("unroll")                                                        \
      for (int ni = 0; ni < 4; ++ni)                                           \
        acc[mi][ni] = __builtin_amdgcn_mfma_f32_16x16x32_bf16(                 \
            av[mi], bv[ni], acc[mi][ni], 0, 0, 0);                             \
  }

#define TILE(t, WSTR)                                                          \
  {                                                                            \
    asm volatile(WSTR ::: "memory");                                           \
    __builtin_amdgcn_sched_barrier(0);                                         \
    __builtin_amdgcn_s_barrier();                                              \
    if ((t) >= 2) YCONS4(((t) - 2) & 1, (t) - 2);                              \
    const char* Ab = smem + ((t) & 1) * 49152;                                 \
    const char* Bb = Ab + 32768;                                               \
    bf16x8 a0[4], b0[4];                                                       \
    FRAGS(a0, b0, cb0, Ab, Bb);                                                \
    if ((t) < 15) STAGE_P1(((t) + 1) & 1, (t) + 1);                            \
    asm volatile("s_waitcnt lgkmcnt(0)" ::: "memory");                         \
    __builtin_amdgcn_sched_barrier(0);                                         \
    __builtin_amdgcn_s_setprio(1);                                             \
    MM16(a0, b0);                                                              \
    __builtin_amdgcn_s_setprio(0);                                             \
    bf16x8 a1[4], b1[4];                                                       \
    FRAGS(a1, b1, cb1, Ab, Bb);                                                \
    if ((t) < 15) STAGE_P2(((t) + 1) & 1, (t) + 1);                            \
    YLOAD8((t) & 1, t);                                                        \
    asm volatile("s_waitcnt lgkmcnt(0)" ::: "memory");                         \
    __builtin_amdgcn_sched_barrier(0);                                         \
    __builtin_amdgcn_s_setprio(1);                                             \
    MM16(a1, b1);                                                              \
    __builtin_amdgcn_s_setprio(0);                                             \
  }

  // prologue: issue tile-0 staging, then redundant inv reduce (identical
  // fixed order in every block -> identical deterministic inv), using the
  // not-yet-staged buf1 LDS region for the tree.
  STAGE_P1(0, 0);
  STAGE_P2(0, 0);

  float inv;
  {
    float* sm = (float*)(smem + 49152);  // buf1 area, free until tile 1
    if (tid < 256) {
      float bp = (biasp[tid] + biasp[tid + 256]) + (biasp[tid + 512] + biasp[tid + 768]);
      float yp = ypart[tid] + ypart[tid + 256];
      float dp = (tid < 16) ? dotpart[tid] : 0.f;
      sm[tid] = 8192.0f * bp + 0.25f * yp + dp;
    }
    __syncthreads();
#pragma unroll
    for (int off = 128; off > 0; off >>= 1) {
      if (tid < off) sm[tid] += sm[tid + off];
      __syncthreads();
    }
    inv = 8388608.0f / sm[0];  // (B*NP)/S
    __syncthreads();
  }

  TILE(0,  "s_waitcnt vmcnt(0)")
  TILE(1,  "s_waitcnt vmcnt(8)")
  TILE(2,  "s_waitcnt vmcnt(8)")
  TILE(3,  "s_waitcnt vmcnt(8)")
  TILE(4,  "s_waitcnt vmcnt(8)")
  TILE(5,  "s_waitcnt vmcnt(8)")
  TILE(6,  "s_waitcnt vmcnt(8)")
  TILE(7,  "s_waitcnt vmcnt(8)")
  TILE(8,  "s_waitcnt vmcnt(8)")
  TILE(9,  "s_waitcnt vmcnt(8)")
  TILE(10, "s_waitcnt vmcnt(8)")
  TILE(11, "s_waitcnt vmcnt(8)")
  TILE(12, "s_waitcnt vmcnt(8)")
  TILE(13, "s_waitcnt vmcnt(8)")
  TILE(14, "s_waitcnt vmcnt(8)")
  TILE(15, "s_waitcnt vmcnt(8)")

  asm volatile("s_waitcnt vmcnt(0)" ::: "memory");
  __builtin_amdgcn_sched_barrier(0);
  YCONS4(0, 14);
  YCONS4(1, 15);

  // epilogue: acc holds gemm + pooled y; add bias, scale by inv, store f32
  float bpv[4];
#pragma unroll
  for (int ni = 0; ni < 4; ++ni) bpv[ni] = biasp[bn0 + wc * 64 + ni * 16 + c_l];
#pragma unroll
  for (int mi = 0; mi < 4; ++mi) {
#pragma unroll
    for (int ni = 0; ni < 4; ++ni) {
      int col = bn0 + wc * 64 + ni * 16 + c_l;
#pragma unroll
      for (int j = 0; j < 4; ++j) {
        int row = bm0 + wr * 64 + mi * 16 + r_l + j;
        out[(size_t)row * NP + col] = (acc[mi][ni][j] + bpv[ni]) * inv;
      }
    }
  }
}

extern "C" void kernel_launch(void* const* d_in, const int* in_sizes, int n_in,
                              void* d_out, int out_size, void* d_ws, size_t ws_size,
                              hipStream_t stream) {
  (void)in_sizes; (void)n_in; (void)out_size; (void)ws_size;
  const float* x = (const float*)d_in[0];
  const float* y = (const float*)d_in[1];
  const float* W = (const float*)d_in[2];
  const float* bias = (const float*)d_in[3];
  float* out = (float*)d_out;

  char* ws = (char*)d_ws;
  unsigned short* xb = (unsigned short*)(ws);            // 16 MiB
  unsigned short* wp = (unsigned short*)(ws + 16777216); // 2 MiB
  float* biasp = (float*)(ws + 18874368);                // 4 KiB
  float* sxpart = (float*)(ws + 18878464);               // 2 MiB (512x1024)
  float* ypart = (float*)(ws + 20975616);                // 2 KiB (512)
  float* dotpart = (float*)(ws + 20977664);              // 64 B (16)

  hipLaunchKernelGGL(k_prep, dim3(2048), dim3(256), 0, stream,
                     x, W, bias, y, xb, wp, biasp, sxpart, ypart);
  hipLaunchKernelGGL(k_reduce2, dim3(16), dim3(256), 0, stream,
                     sxpart, wp, dotpart);
  hipLaunchKernelGGL(k_gemm, dim3(NBLK), dim3(512), 0, stream,
                     xb, wp, biasp, y, out, dotpart, ypart);
}

// Round 18
// 57.609 us; speedup vs baseline: 1.6723x; 1.3912x over previous
//
#include <hip/hip_runtime.h>
#include <stdint.h>

// pooled[b,o] = x[b,:] . Wp[o,:] + biasp[o] + 0.25*(y[b,n0]+y[b,n0+1]+y[b,n0+64]+y[b,n0+65])
//   o = p*32+q, n0 = 128p+2q; Wp = 2x2-pooled W rows. out = pooled / mean(pooled).
// 3 dispatches: prep (x->bf16 + pool W/bias) -> gemm (256x128 tile, 8 waves,
// dbuf LDS, ONE barrier + ONE counted vmcnt(8) per K-tile, 2 setprio'd MFMA
// clusters per tile, y interleaved lag-2 into acc) -> norm (reduce + scale).
// [Round 18: verbatim restore of the round-11 best (57.31 us).]

#define KDIM 1024
#define NP   1024
#define BM 256
#define BN 128
#define BK 64
#define NBLK 256

typedef __bf16 bf16x8 __attribute__((ext_vector_type(8)));
typedef float f32x4 __attribute__((ext_vector_type(4)));
typedef _Float16 f16x4 __attribute__((ext_vector_type(4)));

__device__ __forceinline__ unsigned f2bf(float f) {
  union { float f; unsigned u; } v; v.f = f;
  unsigned r = v.u + 0x7fffu + ((v.u >> 16) & 1u);  // RNE
  return r >> 16;
}

__device__ __forceinline__ void gload_lds16(const void* g, void* l) {
  __builtin_amdgcn_global_load_lds(
      (const __attribute__((address_space(1))) void*)g,
      (__attribute__((address_space(3))) void*)l, 16, 0, 0);
}

// ---- kernel 1 (merged prep): x fp32->bf16 (blocks 0..4095), pool W+bias ----
__global__ void k_prep(const float* __restrict__ x, const float* __restrict__ W,
                       const float* __restrict__ bias,
                       unsigned short* __restrict__ xb, unsigned short* __restrict__ wp,
                       float* __restrict__ biasp) {
  int b = blockIdx.x;
  int t = threadIdx.x;
  if (b < 4096) {
    int i = b * 256 + t;  // 8 elems per thread
    const float4* x4 = (const float4*)x;
    float4 a = x4[i * 2], c = x4[i * 2 + 1];
    uint4 o;
    o.x = f2bf(a.x) | (f2bf(a.y) << 16);
    o.y = f2bf(a.z) | (f2bf(a.w) << 16);
    o.z = f2bf(c.x) | (f2bf(c.y) << 16);
    o.w = f2bf(c.z) | (f2bf(c.w) << 16);
    ((uint4*)xb)[i] = o;
  } else {
    int o = b - 4096;  // pooled feature index
    int r0 = ((o >> 5) << 7) + ((o & 31) << 1);
    const float4* W4 = (const float4*)W;
    float4 w0 = W4[(r0) * 256 + t];
    float4 w1 = W4[(r0 + 1) * 256 + t];
    float4 w2 = W4[(r0 + 64) * 256 + t];
    float4 w3 = W4[(r0 + 65) * 256 + t];
    float ax = 0.25f * (w0.x + w1.x + w2.x + w3.x);
    float ay = 0.25f * (w0.y + w1.y + w2.y + w3.y);
    float az = 0.25f * (w0.z + w1.z + w2.z + w3.z);
    float aw = 0.25f * (w0.w + w1.w + w2.w + w3.w);
    uint2 pk;
    pk.x = f2bf(ax) | (f2bf(ay) << 16);
    pk.y = f2bf(az) | (f2bf(aw) << 16);
    ((uint2*)wp)[o * 256 + t] = pk;
    if (t == 0)
      biasp[o] = 0.25f * (bias[r0] + bias[r0 + 1] + bias[r0 + 64] + bias[r0 + 65]);
  }
}

// ---- kernel 2: GEMM 256x128, 1 barrier + 1 vmcnt per K-tile ----
__global__ __launch_bounds__(512, 2) void k_gemm(
    const unsigned short* __restrict__ xb, const unsigned short* __restrict__ wp,
    const float* __restrict__ biasp, const float* __restrict__ y,
    float* __restrict__ out, _Float16* __restrict__ ph,
    float* __restrict__ partials, int use16) {
  // buf in {0,1}: A(buf)=smem+buf*49152 (32KB), B(buf)=+32768 (16KB)
  __shared__ char smem[98304];

  int bid = blockIdx.x;
  int wg = (bid & 7) * 32 + (bid >> 3);  // XCD swizzle, 256 = 8*32 bijective
  int bm0 = (wg >> 3) * BM;   // 32 row tiles
  int bn0 = (wg & 7) * BN;    // 8 col tiles

  int tid = threadIdx.x;
  int lane = tid & 63;
  int wid = tid >> 6;               // 0..7
  int wr = wid >> 1, wc = wid & 1;  // wave tile 64x64

  f32x4 acc[4][4];
#pragma unroll
  for (int i = 0; i < 4; i++)
#pragma unroll
    for (int j = 0; j < 4; j++) acc[i][j] = (f32x4)0.0f;

  // staging: 512 thr x 16B = 8KB/call; A 32KB = 4 calls, B 16KB = 2 calls.
  // LDS dest linear; SOURCE col chunk pre-swizzled by (lane&7)^(lane>>3).
  int srow = tid >> 3;  // 0..63
  int scol = (((lane & 7) ^ (lane >> 3)) << 3);
  const unsigned short* aSrc = xb + (size_t)(bm0 + srow) * KDIM + scol;
  const unsigned short* bSrc = wp + (size_t)(bn0 + srow) * KDIM + scol;
  int ldsOff = wid * 1024;

  int rbase = (lane & 15) * 128;
  int xorv = (lane & 7) << 4;
  int cb0 = (((lane >> 4) * 16)) ^ xorv;
  int cb1 = ((64 + (lane >> 4) * 16)) ^ xorv;

  // y: tile p covers fragment (mi=p>>2, ni=p&3), j=0..3 -> 8 dwordx2/tile.
  const float2* y2 = (const float2*)y;
  int r_l = (lane >> 4) * 4;
  int c_l = lane & 15;
  int yrb = bm0 + wr * 64 + r_l;
  int yb[4];
#pragma unroll
  for (int ni = 0; ni < 4; ++ni) {
    int col = bn0 + wc * 64 + ni * 16 + c_l;
    yb[ni] = ((col >> 5) << 6) + (col & 31);
  }
  float2 yin[2][8];  // 2-slot rotating window

#define STAGE_P1(buf, ks)                                                      \
  {                                                                            \
    int k0 = (ks) * BK;                                                        \
    char* ab = smem + (buf) * 49152 + ldsOff;                                  \
    gload_lds16(aSrc + k0, ab);                                                \
    gload_lds16(aSrc + (size_t)64 * KDIM + k0, ab + 8192);                     \
    gload_lds16(aSrc + (size_t)128 * KDIM + k0, ab + 16384);                   \
  }
#define STAGE_P2(buf, ks)                                                      \
  {                                                                            \
    int k0 = (ks) * BK;                                                        \
    char* ab = smem + (buf) * 49152 + ldsOff;                                  \
    char* bb = smem + (buf) * 49152 + 32768 + ldsOff;                          \
    gload_lds16(aSrc + (size_t)192 * KDIM + k0, ab + 24576);                   \
    gload_lds16(bSrc + k0, bb);                                                \
    gload_lds16(bSrc + (size_t)64 * KDIM + k0, bb + 8192);                     \
  }

#define YLD2(slot, s, q)                                                       \
  {                                                                            \
    const float2* pp = y2 +                                                    \
        (size_t)(yrb + (((q) >> 4) * 16) + ((q) & 3)) * 2048 + yb[((q) >> 2) & 3]; \
    asm volatile("global_load_dwordx2 %0, %1, off"                             \
                 : "=v"(yin[slot][2 * (s)]) : "v"(pp) : "memory");             \
    asm volatile("global_load_dwordx2 %0, %1, off offset:256"                  \
                 : "=v"(yin[slot][2 * (s) + 1]) : "v"(pp) : "memory");         \
  }
#define YLOAD8(slot, t)                                                        \
  { YLD2(slot, 0, 4 * (t)) YLD2(slot, 1, 4 * (t) + 1)                          \
    YLD2(slot, 2, 4 * (t) + 2) YLD2(slot, 3, 4 * (t) + 3) }
// tile p's 4 y-values are the 4 j's of fragment acc[p>>2][p&3]
#define YCONS4(slot, p)                                                        \
  {                                                                            \
    _Pragma("unroll")                                                          \
    for (int s = 0; s < 4; ++s)                                                \
      acc[(p) >> 2][(p) & 3][s] +=                                             \
          0.25f * ((yin[slot][2 * s].x + yin[slot][2 * s].y) +                 \
                   (yin[slot][2 * s + 1].x + yin[slot][2 * s + 1].y));         \
  }

#define FRAGS(av, bv, cbv, Ab, Bb)                                             \
  {                                                                            \
    _Pragma("unroll")                                                          \
    for (int mi = 0; mi < 4; ++mi)                                             \
      av[mi] = *(const bf16x8*)((Ab) + (wr * 64 + mi * 16) * 128 + rbase + (cbv)); \
    _Pragma("unroll")                                                          \
    for (int ni = 0; ni < 4; ++ni)                                             \
      bv[ni] = *(const bf16x8*)((Bb) + (wc * 64 + ni * 16) * 128 + rbase + (cbv)); \
  }
#define MM16(av, bv)                                                           \
  {                                                                            \
    _Pragma("unroll")                                                          \
    for (int mi = 0; mi < 4; ++mi)                                             \
      _Pragma("unroll")                                                        \
      for (int ni = 0; ni < 4; ++ni)                                           \
        acc[mi][ni] = __builtin_amdgcn_mfma_f32_16x16x32_bf16(                 \
            av[mi], bv[ni], acc[mi][ni], 0, 0, 0);                             \
  }

  // Per K-tile: wait vmcnt(8) (S_t retired, only Y_{t-1} in flight) -> barrier
  // -> consume Y_{t-2} -> {frags kk0 | stage P1(t+1)} lgkm0 MFMA -> {frags kk1
  // | stage P2(t+1) | YLOAD(t)} lgkm0 MFMA.  S_{t+1} writes the buffer tile
  // t-1 vacated (safe: issued after t's barrier). Never drains mid-loop.
#define TILE(t, WSTR)                                                          \
  {                                                                            \
    asm volatile(WSTR ::: "memory");                                           \
    __builtin_amdgcn_sched_barrier(0);                                         \
    __builtin_amdgcn_s_barrier();                                              \
    if ((t) >= 2) YCONS4(((t) - 2) & 1, (t) - 2);                              \
    const char* Ab = smem + ((t) & 1) * 49152;                                 \
    const char* Bb = Ab + 32768;                                               \
    bf16x8 a0[4], b0[4];                                                       \
    FRAGS(a0, b0, cb0, Ab, Bb);                                                \
    if ((t) < 15) STAGE_P1(((t) + 1) & 1, (t) + 1);                            \
    asm volatile("s_waitcnt lgkmcnt(0)" ::: "memory");                         \
    __builtin_amdgcn_sched_barrier(0);                                         \
    __builtin_amdgcn_s_setprio(1);                                             \
    MM16(a0, b0);                                                              \
    __builtin_amdgcn_s_setprio(0);                                             \
    bf16x8 a1[4], b1[4];                                                       \
    FRAGS(a1, b1, cb1, Ab, Bb);                                                \
    if ((t) < 15) STAGE_P2(((t) + 1) & 1, (t) + 1);                            \
    YLOAD8((t) & 1, t);                                                        \
    asm volatile("s_waitcnt lgkmcnt(0)" ::: "memory");                         \
    __builtin_amdgcn_sched_barrier(0);                                         \
    __builtin_amdgcn_s_setprio(1);                                             \
    MM16(a1, b1);                                                              \
    __builtin_amdgcn_s_setprio(0);                                             \
  }

  // prologue: stage tile 0 fully
  STAGE_P1(0, 0);
  STAGE_P2(0, 0);

  TILE(0,  "s_waitcnt vmcnt(0)")
  TILE(1,  "s_waitcnt vmcnt(8)")
  TILE(2,  "s_waitcnt vmcnt(8)")
  TILE(3,  "s_waitcnt vmcnt(8)")
  TILE(4,  "s_waitcnt vmcnt(8)")
  TILE(5,  "s_waitcnt vmcnt(8)")
  TILE(6,  "s_waitcnt vmcnt(8)")
  TILE(7,  "s_waitcnt vmcnt(8)")
  TILE(8,  "s_waitcnt vmcnt(8)")
  TILE(9,  "s_waitcnt vmcnt(8)")
  TILE(10, "s_waitcnt vmcnt(8)")
  TILE(11, "s_waitcnt vmcnt(8)")
  TILE(12, "s_waitcnt vmcnt(8)")
  TILE(13, "s_waitcnt vmcnt(8)")
  TILE(14, "s_waitcnt vmcnt(8)")
  TILE(15, "s_waitcnt vmcnt(8)")

  asm volatile("s_waitcnt vmcnt(0)" ::: "memory");
  __builtin_amdgcn_sched_barrier(0);
  YCONS4(0, 14);
  YCONS4(1, 15);

  // epilogue: acc holds gemm + pooled y; add bias, store, block sum
  float tsum = 0.f;
  float bpv[4];
#pragma unroll
  for (int ni = 0; ni < 4; ++ni) bpv[ni] = biasp[bn0 + wc * 64 + ni * 16 + c_l];
#pragma unroll
  for (int mi = 0; mi < 4; ++mi) {
#pragma unroll
    for (int ni = 0; ni < 4; ++ni) {
      int col = bn0 + wc * 64 + ni * 16 + c_l;
#pragma unroll
      for (int j = 0; j < 4; ++j) {
        int row = bm0 + wr * 64 + mi * 16 + r_l + j;
        float val = acc[mi][ni][j] + bpv[ni];
        size_t o = (size_t)row * NP + col;
        if (use16) ph[o] = (_Float16)val;
        else out[o] = val;
        tsum += val;
      }
    }
  }
#pragma unroll
  for (int off = 32; off > 0; off >>= 1) tsum += __shfl_down(tsum, off);
  float* sm = (float*)smem;
  __syncthreads();
  if (lane == 0) sm[wid] = tsum;
  __syncthreads();
  if (tid == 0)
    partials[bid] = ((sm[0] + sm[1]) + (sm[2] + sm[3])) +
                    ((sm[4] + sm[5]) + (sm[6] + sm[7]));
}

// ---- kernel 3: redundant per-block reduce of 256 partials; scale to f32 out ----
__global__ void k_norm(float* __restrict__ out, const _Float16* __restrict__ ph,
                       const float* __restrict__ partials, int use16) {
  __shared__ float s[256];
  int t = threadIdx.x;
  s[t] = partials[t];
  __syncthreads();
#pragma unroll
  for (int off = 128; off > 0; off >>= 1) {
    if (t < off) s[t] += s[t + off];
    __syncthreads();
  }
  float inv = 8388608.0f / s[0];  // (B*NP)/total
  int i = blockIdx.x * 256 + t;   // float4 index
  float4* o4 = (float4*)out;
  if (use16) {
    f16x4 hv = ((const f16x4*)ph)[i];
    float4 v;
    v.x = (float)hv[0] * inv;
    v.y = (float)hv[1] * inv;
    v.z = (float)hv[2] * inv;
    v.w = (float)hv[3] * inv;
    o4[i] = v;
  } else {
    float4 v = o4[i];
    v.x *= inv; v.y *= inv; v.z *= inv; v.w *= inv;
    o4[i] = v;
  }
}

extern "C" void kernel_launch(void* const* d_in, const int* in_sizes, int n_in,
                              void* d_out, int out_size, void* d_ws, size_t ws_size,
                              hipStream_t stream) {
  (void)in_sizes; (void)n_in; (void)out_size;
  const float* x = (const float*)d_in[0];
  const float* y = (const float*)d_in[1];
  const float* W = (const float*)d_in[2];
  const float* bias = (const float*)d_in[3];
  float* out = (float*)d_out;

  char* ws = (char*)d_ws;
  unsigned short* xb = (unsigned short*)(ws);                 // 16 MiB
  unsigned short* wp = (unsigned short*)(ws + 16777216);      // 2 MiB
  float* biasp = (float*)(ws + 16777216 + 2097152);           // 4 KiB
  float* partials = (float*)(ws + 16777216 + 2097152 + 4096); // 1 KiB
  _Float16* ph = (_Float16*)(ws + 20971520);                  // 16 MiB
  int use16 = (ws_size >= (size_t)20971520 + 16777216) ? 1 : 0;

  hipLaunchKernelGGL(k_prep, dim3(5120), dim3(256), 0, stream, x, W, bias, xb, wp, biasp);
  hipLaunchKernelGGL(k_gemm, dim3(NBLK), dim3(512), 0, stream, xb, wp, biasp, y, out, ph, partials, use16);
  hipLaunchKernelGGL(k_norm, dim3(8192), dim3(256), 0, stream, out, ph, partials, use16);
}